// Round 1
// 4078.080 us; speedup vs baseline: 1.0279x; 1.0279x over previous
//
#include <hip/hip_runtime.h>
#include <cstdint>
#include <cstddef>

// ---------------- constants (from reference) ----------------
constexpr int   Dm    = 1024;
constexpr int   NHn   = 16;
constexpr int   NKVn  = 4;
constexpr int   HDn   = 64;
constexpr int   Ln    = 6;
constexpr int   Sn    = 2048;
constexpr int   Bn    = 2;
constexpr int   ROWS  = Bn * Sn;          // 4096 token rows
constexpr int   VSn   = 50257;
constexpr int   HSn   = 4096;
constexpr float EPSF  = 1.1920929e-07f;
constexpr int   VCHUNK = 4096;            // vocab chunk for LM head
constexpr int   VPAD   = 50304;           // 393*128
constexpr float LOG2E  = 1.44269504f;

#define DEV __device__ __forceinline__

typedef __attribute__((ext_vector_type(8))) short bf16x8;
typedef __attribute__((ext_vector_type(4))) float f32x4;
using ush = unsigned short;

DEV ush f2bf(float f) {
    unsigned int u = __float_as_uint(f);
    u = (u + 0x7fffu + ((u >> 16) & 1u)) >> 16;
    return (ush)u;
}

DEV float b2f(ush v) {
    return __uint_as_float(((unsigned int)v) << 16);
}

DEV f32x4 mfma16(bf16x8 a, bf16x8 b, f32x4 c) {
    return __builtin_amdgcn_mfma_f32_16x16x32_bf16(a, b, c, 0, 0, 0);
}

DEV void llds16(const ush* g, ush* l) {
    __builtin_amdgcn_global_load_lds(
        (const __attribute__((address_space(1))) void*)g,
        (__attribute__((address_space(3))) void*)l, 16, 0, 0);
}

// raw workgroup barrier with compiler memory fences (no vmcnt(0) drain)
DEV void bar() {
    asm volatile("" ::: "memory");
    __builtin_amdgcn_s_barrier();
    asm volatile("" ::: "memory");
}

// ---------------- block reductions (256 threads = 4 waves) ----------------
DEV float block_sum256(float v, float* red) {
#pragma unroll
    for (int off = 32; off; off >>= 1) v += __shfl_xor(v, off);
    __syncthreads();
    if ((threadIdx.x & 63) == 0) red[threadIdx.x >> 6] = v;
    __syncthreads();
    return red[0] + red[1] + red[2] + red[3];
}

DEV float block_max256(float v, float* red) {
#pragma unroll
    for (int off = 32; off; off >>= 1) v = fmaxf(v, __shfl_xor(v, off));
    __syncthreads();
    if ((threadIdx.x & 63) == 0) red[threadIdx.x >> 6] = v;
    __syncthreads();
    return fmaxf(fmaxf(red[0], red[1]), fmaxf(red[2], red[3]));
}

// ---------------- rope tables ----------------
__global__ void rope_kernel(float* __restrict__ cb, float* __restrict__ sb) {
    int idx = blockIdx.x * 256 + threadIdx.x;
    if (idx >= Sn * 32) return;
    int t = idx >> 5, f = idx & 31;
    float freq = powf(10000.f, -(float)f * (1.f / 32.f));
    float ang  = (float)t * freq;
    cb[idx] = cosf(ang);
    sb[idx] = sinf(ang);
}

// ---------------- fp32 -> bf16 convert / zero pad ----------------
__global__ void cvt_bf16_kernel(const float* __restrict__ s, ush* __restrict__ d, int n4) {
    int i = blockIdx.x * 256 + threadIdx.x;
    if (i >= n4) return;
    float4 v = *(const float4*)(s + (size_t)i * 4);
    ushort4 o;
    o.x = f2bf(v.x); o.y = f2bf(v.y); o.z = f2bf(v.z); o.w = f2bf(v.w);
    *(ushort4*)(d + (size_t)i * 4) = o;
}

__global__ void zpad_kernel(ush* __restrict__ p, int n) {
    int i = blockIdx.x * 256 + threadIdx.x;
    if (i < n) p[i] = 0;
}

// ---------------- embedding + rmsn ----------------
__global__ __launch_bounds__(256)
void embed_kernel(const int* __restrict__ ids, const float* __restrict__ ue,
                  const float* __restrict__ be, float* __restrict__ h,
                  float* __restrict__ h0) {
    __shared__ float red[4];
    int r = blockIdx.x;
    int s = r % Sn;
    int id = ids[r];
    int prev = (s == 0) ? 0 : ids[r - 1];
    int bi = ((prev % HSn) * (VSn % HSn) % HSn + id % HSn) % HSn;
    int tid = threadIdx.x;
    float vals[4];
    float ss = 0.f;
#pragma unroll
    for (int t = 0; t < 4; ++t) {
        int j = tid + t * 256;
        float v = (j < 512) ? ue[(size_t)id * 512 + j]
                            : be[(size_t)bi * 512 + (j - 512)];
        vals[t] = v; ss += v * v;
    }
    ss = block_sum256(ss, red);
    float rinv = rsqrtf(ss * (1.f / Dm) + EPSF);
#pragma unroll
    for (int t = 0; t < 4; ++t) {
        int j = tid + t * 256;
        float v = vals[t] * rinv;
        h [(size_t)r * Dm + j] = v;
        h0[(size_t)r * Dm + j] = v;
    }
}

// ---------------- (optional skip add) + residual mix + rmsn -> bf16 ----------------
template<bool SKIP>
__global__ __launch_bounds__(256)
void resmix_kernel(float* __restrict__ h, const float* __restrict__ h0,
                   const float* __restrict__ rm0, ush* __restrict__ xnb,
                   const ush* __restrict__ skb, const float* __restrict__ sw) {
    __shared__ float red[4];
    int r = blockIdx.x, tid = threadIdx.x;
    const float* rm1 = rm0 + Dm;
    float vals[4]; float ss = 0.f;
#pragma unroll
    for (int t = 0; t < 4; ++t) {
        int j = tid + t * 256;
        size_t o = (size_t)r * Dm + j;
        float base = h[o];
        if (SKIP) base = fmaf(sw[j], b2f(skb[o]), base);
        float v = rm0[j] * base + rm1[j] * h0[o];
        vals[t] = v; ss += v * v;
        h[o] = v;
    }
    ss = block_sum256(ss, red);
    float rinv = rsqrtf(ss * (1.f / Dm) + EPSF);
#pragma unroll
    for (int t = 0; t < 4; ++t)
        xnb[(size_t)r * Dm + tid + t * 256] = f2bf(vals[t] * rinv);
}

// ---------------- standalone rmsn -> bf16 ----------------
__global__ __launch_bounds__(256)
void rmsn_kernel(const float* __restrict__ x, ush* __restrict__ out) {
    __shared__ float red[4];
    int r = blockIdx.x, tid = threadIdx.x;
    float vals[4]; float ss = 0.f;
#pragma unroll
    for (int t = 0; t < 4; ++t) {
        float v = x[(size_t)r * Dm + tid + t * 256];
        vals[t] = v; ss += v * v;
    }
    ss = block_sum256(ss, red);
    float rinv = rsqrtf(ss * (1.f / Dm) + EPSF);
#pragma unroll
    for (int t = 0; t < 4; ++t)
        out[(size_t)r * Dm + tid + t * 256] = f2bf(vals[t] * rinv);
}

// ---------------- bf16 MFMA GEMM: C(MxN) = A(MxK) @ B(NxK)^T ----------------
// TM in {64,128}. MODE 0: bf16 store  1: relu^2 bf16  2: 30*tanh(v/30) bf16
// MODE 3: residual add  h[row*ldc+col] += sc[col]*acc  (+ optional bf16 dup)
//
// Depth-2 software pipeline: 3 LDS buffers; stage(t+2) issued before compute(t);
// counted s_waitcnt vmcnt(LPS) keeps the next stage in flight across the raw
// s_barrier (no compiler-forced vmcnt(0) drain). LDS is chunk-swizzled
// (16B chunk ^= (row>>1)&3) on BOTH the per-lane global source address and the
// ds_read address (global_load_lds dest must stay linear), which takes the
// frag ds_read_b128 from an 8-way bank conflict to 2-way (free).
template<int TM, int MODE>
__global__ __launch_bounds__(256)
void gemm_k(const ush* __restrict__ A, const ush* __restrict__ B,
            ush* __restrict__ C, int M, int N, int K,
            int lda, int ldb, int ldc,
            float* __restrict__ hres, const float* __restrict__ sc,
            ush* __restrict__ dup) {
    constexpr int ASZ = TM * 32;
    __shared__ __align__(16) ush As[3][ASZ];
    __shared__ __align__(16) ush Bs[3][128 * 32];
    const int m0 = blockIdx.x * TM, n0 = blockIdx.y * 128;
    const int tid  = threadIdx.x;
    const int w    = tid >> 6, lane = tid & 63;
    const int l15  = lane & 15, quad = lane >> 4;
    const int wr   = w >> 1, wc = w & 1;
    constexpr int NI = TM / 32;        // acc row-tiles per wave (4 or 2)

    const int srow = lane >> 2;
    const int schs = (lane & 3) ^ ((srow >> 1) & 3);   // swizzled source chunk
    const ush* Ag;
    int aoff;
    if constexpr (TM == 128) {
        Ag   = A + (size_t)(m0 + w * 32 + srow) * lda + schs * 8;
        aoff = w * 1024;
    } else {
        Ag   = A + (size_t)(m0 + w * 16 + srow) * lda + schs * 8;
        aoff = w * 512;
    }
    const ush* Bg  = B + (size_t)(n0 + w * 32 + srow) * ldb + schs * 8;
    const int boff = w * 1024;

    auto stage = [&](int buf, int k0) {
        llds16(Ag + k0, &As[buf][aoff]);
        if constexpr (TM == 128) llds16(Ag + k0 + 16 * lda, &As[buf][aoff + 512]);
        llds16(Bg + k0,            &Bs[buf][boff]);
        llds16(Bg + k0 + 16 * ldb, &Bs[buf][boff + 512]);
    };

    f32x4 acc[NI][4] = {};
    const int nt = K >> 5;

    // prologue: stage tiles 0 and 1, wait for tile 0 only
    stage(0, 0);
    if (nt > 1) {
        stage(1, 32);
        if constexpr (TM == 128) asm volatile("s_waitcnt vmcnt(4)" ::: "memory");
        else                     asm volatile("s_waitcnt vmcnt(3)" ::: "memory");
    } else {
        asm volatile("s_waitcnt vmcnt(0)" ::: "memory");
    }
    bar();

    const int cso = (quad ^ ((l15 >> 1) & 3)) * 8;     // swizzled read chunk
    int bcur = 0;
    for (int t = 0; t < nt; ++t) {
        if (t + 2 < nt) {
            int bn = bcur >= 1 ? bcur - 1 : 2;         // (bcur+2)%3
            stage(bn, (t + 2) * 32);
        }
        bf16x8 af[NI], bfv[4];
#pragma unroll
        for (int i = 0; i < NI; ++i)
            af[i] = *(const bf16x8*)&As[bcur][(wr * (TM / 2) + i * 16 + l15) * 32 + cso];
#pragma unroll
        for (int j = 0; j < 4; ++j)
            bfv[j] = *(const bf16x8*)&Bs[bcur][(wc * 64 + j * 16 + l15) * 32 + cso];
#pragma unroll
        for (int i = 0; i < NI; ++i)
#pragma unroll
            for (int j = 0; j < 4; ++j)
                acc[i][j] = mfma16(af[i], bfv[j], acc[i][j]);
        // drain stage(t+1) only; stage(t+2) stays in flight across the barrier
        if (t + 2 < nt) {
            if constexpr (TM == 128) asm volatile("s_waitcnt vmcnt(4)" ::: "memory");
            else                     asm volatile("s_waitcnt vmcnt(3)" ::: "memory");
        } else {
            asm volatile("s_waitcnt vmcnt(0)" ::: "memory");
        }
        bar();
        bcur = bcur == 2 ? 0 : bcur + 1;
    }

#pragma unroll
    for (int i = 0; i < NI; ++i) {
#pragma unroll
        for (int j = 0; j < 4; ++j) {
            int row = m0 + wr * (TM / 2) + i * 16 + quad * 4;
            int col = n0 + wc * 64 + j * 16 + l15;
#pragma unroll
            for (int r = 0; r < 4; ++r) {
                float v = acc[i][j][r];
                if (MODE == 1) { v = fmaxf(v, 0.f); v = v * v; }
                else if (MODE == 2) {
                    float ax = fabsf(v) * (1.f / 30.f);
                    float e  = __expf(-2.f * ax);
                    float t  = (1.f - e) / (1.f + e);
                    v = copysignf(t * 30.f, v);
                }
                if (MODE == 3) {
                    size_t o = (size_t)(row + r) * ldc + col;
                    float nv = fmaf(sc[col], v, hres[o]);
                    hres[o] = nv;
                    if (dup) dup[o] = f2bf(nv);
                } else {
                    C[(size_t)(row + r) * ldc + col] = f2bf(v);
                }
            }
        }
    }
}

// ---------------- fused q+k per-head rmsn + rope -> bf16 ----------------
__global__ __launch_bounds__(256)
void qknorm_rope_kernel(const ush* __restrict__ in,
                        ush* __restrict__ qout, ush* __restrict__ kout,
                        const float* __restrict__ cosb, const float* __restrict__ sinb,
                        const float* __restrict__ qg) {
    int idx  = blockIdx.x * 4 + (threadIdx.x >> 6);
    int lane = threadIdx.x & 63;
    int t, hh, in_off;
    ush* outp; int out_ld;
    bool isq = idx < ROWS * NHn;
    if (isq) { t = idx >> 4; hh = idx & 15; in_off = hh * 64; outp = qout; out_ld = 1024; }
    else { int i2 = idx - ROWS * NHn; t = i2 >> 2; hh = i2 & 3; in_off = 1024 + hh * 64; outp = kout; out_ld = 256; }
    int sidx = t % Sn;
    float x = b2f(in[(size_t)t * 1536 + in_off + lane]);
    float ss = x * x;
#pragma unroll
    for (int off = 32; off; off >>= 1) ss += __shfl_xor(ss, off);
    float xn = x * rsqrtf(ss * (1.f / HDn) + EPSF);
    float partner = __shfl_xor(xn, 32);
    int f = lane & 31;
    float c  = cosb[sidx * 32 + f];
    float sv = sinb[sidx * 32 + f];
    float o = (lane < 32) ? fmaf(xn, c, partner * sv)
                          : fmaf(xn, c, -partner * sv);
    if (isq) o *= qg[hh] * (0.125f * LOG2E);
    outp[(size_t)t * out_ld + hh * 64 + lane] = f2bf(o);
}

// ---------------- V transpose: bf16 [4096][1536] (cols 1280..1535) -> bf16 [256][4096] ----------------
__global__ __launch_bounds__(256)
void vtrans_kernel(const ush* __restrict__ in, ush* __restrict__ out) {
    __shared__ ush tile[32][33];
    int s0 = blockIdx.x * 32;
    int c0 = blockIdx.y * 32;
    int i = threadIdx.x >> 5;
    int j = threadIdx.x & 31;
#pragma unroll
    for (int k = 0; k < 4; ++k)
        tile[i + k * 8][j] = in[(size_t)(s0 + i + k * 8) * 1536 + 1280 + c0 + j];
    __syncthreads();
#pragma unroll
    for (int k = 0; k < 4; ++k)
        out[(size_t)(c0 + i + k * 8) * (size_t)ROWS + s0 + j] = tile[j][i + k * 8];
}

// ---------------- causal GQA flash attention, split-K, bf16 MFMA ----------------
// Static-max softmax => KV chunks combine by plain addition. Each block:
// (b, h, q-tile of 128 rows, 512-key chunk). Unnormalized O-partials (bf16)
// + l-partials (fp32) written to global; combine kernel normalizes.
// Per (b,h): tiles t=0..15, chunks c=0..(t>>2). 40 pairs -> grid 1280.
__global__ __launch_bounds__(256)
void attn_mfma_kernel(const ush* __restrict__ qb,
                      const ush* __restrict__ kb,
                      const ush* __restrict__ vt,
                      ush* __restrict__ opart,
                      float* __restrict__ lpart,
                      const float* __restrict__ qgl) {
    __shared__ __align__(16) ush Ks[64 * 72];
    __shared__ __align__(16) ush Vs[64 * 72];
    __shared__ __align__(16) unsigned int PsD[128 * 36];
    // decode (b, h, tile t, chunk c)
    const int pair = blockIdx.x % 40;
    const int bh   = blockIdx.x / 40;
    const int h    = bh & 15;
    const int b    = bh >> 4;
    const int g    = (pair >= 24) ? 3 : (pair >= 12) ? 2 : (pair >= 4) ? 1 : 0;
    const int off_p = pair - 2 * g * (g + 1);
    const int t    = 4 * g + off_p / (g + 1);
    const int c    = off_p % (g + 1);
    const int kvh  = h >> 2;
    const int w    = threadIdx.x >> 6, lane = threadIdx.x & 63;
    const int l15  = lane & 15, quad = lane >> 4;
    const int q0   = t * 128;
    const int k_lo = c * 512;
    const int k_hi_full = (t + 1) * 128;
    const int k_hi = (k_lo + 512 < k_hi_full) ? (k_lo + 512) : k_hi_full;
    const int nblk = (k_hi - k_lo) >> 6;
    const float mfix = 8.f * fabsf(qgl[h]) * LOG2E;

    // Q fragments: wave w covers q rows q0+w*32 .. +31 (frags f=0,1)
    bf16x8 qf[2][2];
    {
        size_t qr = (size_t)(b * Sn + q0 + w * 32 + l15) * 1024 + h * 64;
        qf[0][0] = *(const bf16x8*)(qb + qr + quad * 8);
        qf[0][1] = *(const bf16x8*)(qb + qr + 32 + quad * 8);
        qf[1][0] = *(const bf16x8*)(qb + qr + 16 * 1024 + quad * 8);
        qf[1][1] = *(const bf16x8*)(qb + qr + 16 * 1024 + 32 + quad * 8);
    }
    f32x4 Oacc[2][4] = {};
    float lsum[2][4] = {{0.f,0.f,0.f,0.f},{0.f,0.f,0.f,0.f}};

    const int rrS = threadIdx.x >> 3, chS = threadIdx.x & 7;
    const size_t kbase = (size_t)(b * Sn) * 256 + kvh * 64;
    const size_t vbase = (size_t)(kvh * 64) * (size_t)ROWS + b * Sn;

    // prologue prefetch of first KV block
    uint4 kr0 = *(const uint4*)(kb + kbase + (size_t)(k_lo + rrS) * 256 + chS * 8);
    uint4 kr1 = *(const uint4*)(kb + kbase + (size_t)(k_lo + rrS + 32) * 256 + chS * 8);
    uint4 vr0 = *(const uint4*)(vt + vbase + (size_t)rrS * ROWS + k_lo + chS * 8);
    uint4 vr1 = *(const uint4*)(vt + vbase + (size_t)(rrS + 32) * ROWS + k_lo + chS * 8);

    for (int kb_i = 0; kb_i < nblk; ++kb_i) {
        const int k0 = k_lo + kb_i * 64;
        __syncthreads();                       // prev iter's LDS reads done
        *(uint4*)&Ks[rrS * 72 + chS * 8]        = kr0;
        *(uint4*)&Ks[(rrS + 32) * 72 + chS * 8] = kr1;
        *(uint4*)&Vs[rrS * 72 + chS * 8]        = vr0;
        *(uint4*)&Vs[(rrS + 32) * 72 + chS * 8] = vr1;
        __syncthreads();
        if (kb_i + 1 < nblk) {                 // prefetch next block (overlaps compute)
            int k0n = k0 + 64;
            kr0 = *(const uint4*)(kb + kbase + (size_t)(k0n + rrS) * 256 + chS * 8);
            kr1 = *(const uint4*)(kb + kbase + (size_t)(k0n + rrS + 32) * 256 + chS * 8);
            vr0 = *(const uint4*)(vt + vbase + (size_t)rrS * ROWS + k0n + chS * 8);
            vr1 = *(const uint4*)(vt + vbase + (size_t)(rrS + 32) * ROWS + k0n + chS * 8);
        }

        // QK^T for both q-frags
        f32x4 S0[4] = {}, S1[4] = {};
#pragma unroll
        for (int cc = 0; cc < 4; ++cc) {
            bf16x8 kf0 = *(const bf16x8*)&Ks[(cc * 16 + l15) * 72 + quad * 8];
            bf16x8 kf1 = *(const bf16x8*)&Ks[(cc * 16 + l15) * 72 + 32 + quad * 8];
            S0[cc] = mfma16(qf[0][0], kf0, S0[cc]);
            S0[cc] = mfma16(qf[0][1], kf1, S0[cc]);
            S1[cc] = mfma16(qf[1][0], kf0, S1[cc]);
            S1[cc] = mfma16(qf[1][1], kf1, S1[cc]);
        }

#pragma unroll
        for (int f = 0; f < 2; ++f) {
            f32x4* S = f ? S1 : S0;
            const int qbF = q0 + w * 32 + f * 16;
            if (k0 + 63 > qbF) {               // diagonal-adjacent: mask
#pragma unroll
                for (int cc = 0; cc < 4; ++cc) {
                    int key = k0 + cc * 16 + l15;
#pragma unroll
                    for (int r = 0; r < 4; ++r)
                        if (key > qbF + quad * 4 + r) S[cc][r] = -INFINITY;
                }
            }
#pragma unroll
            for (int cc = 0; cc < 4; ++cc)
#pragma unroll
                for (int r = 0; r < 4; ++r) {
                    float p = exp2f(S[cc][r] - mfix);
                    S[cc][r] = p;
                    lsum[f][r] += p;
                }
            // pack (k, k+32) bf16 pairs (truncating) and store to LDS
            const int prow = w * 32 + f * 16 + quad * 4;
#pragma unroll
            for (int cp = 0; cp < 2; ++cp)
#pragma unroll
                for (int r = 0; r < 4; ++r) {
                    unsigned int pk = __builtin_amdgcn_perm(
                        __float_as_uint(S[cp + 2][r]), __float_as_uint(S[cp][r]),
                        0x07060302u);
                    PsD[(prow + r) * 36 + cp * 16 + l15] = pk;
                }
        }

        // PV for both q-frags
#pragma unroll
        for (int f = 0; f < 2; ++f) {
            const int prow = w * 32 + f * 16 + l15;
            unsigned int d[8];
            *(uint4*)&d[0] = *(const uint4*)&PsD[prow * 36 + quad * 8];
            *(uint4*)&d[4] = *(const uint4*)&PsD[prow * 36 + quad * 8 + 4];
            unsigned int lo[4], hi[4];
#pragma unroll
            for (int tt = 0; tt < 4; ++tt) {
                lo[tt] = __builtin_amdgcn_perm(d[2 * tt + 1], d[2 * tt], 0x05040100u);
                hi[tt] = __builtin_amdgcn_perm(d[2 * tt + 1], d[2 * tt], 0x07060302u);
            }
            bf16x8 pf0 = *(const bf16x8*)lo;
            bf16x8 pf1 = *(const bf16x8*)hi;
#pragma unroll
            for (int dt = 0; dt < 4; ++dt) {
                bf16x8 vf0 = *(const bf16x8*)&Vs[(dt * 16 + l15) * 72 + quad * 8];
                bf16x8 vf1 = *(const bf16x8*)&Vs[(dt * 16 + l15) * 72 + 32 + quad * 8];
                Oacc[f][dt] = mfma16(pf0, vf0, Oacc[f][dt]);
                Oacc[f][dt] = mfma16(pf1, vf1, Oacc[f][dt]);
            }
        }
    }

    // deferred l-reduction + unnormalized epilogue
#pragma unroll
    for (int f = 0; f < 2; ++f) {
#pragma unroll
        for (int m = 1; m <= 8; m <<= 1)
#pragma unroll
            for (int r = 0; r < 4; ++r)
                lsum[f][r] += __shfl_xor(lsum[f][r], m);
#pragma unroll
        for (int r = 0; r < 4; ++r) {
            int token = b * Sn + q0 + w * 32 + f * 16 + quad * 4 + r;
            if (l15 == 0)
                lpart[((size_t)c * ROWS + token) * NHn + h] = lsum[f][r];
#pragma unroll
            for (int dt = 0; dt < 4; ++dt)
                opart[((size_t)c * ROWS + token) * 1024 + h * 64 + dt * 16 + l15]
                    = f2bf(Oacc[f][dt][r]);
        }
    }
}

// ---------------- combine split-K partials: attb = sum(O)/sum(l) ----------------
__global__ __launch_bounds__(256)
void attn_combine_kernel(const ush* __restrict__ opart,
                         const float* __restrict__ lpart,
                         ush* __restrict__ attb) {
    int token = blockIdx.x;
    int j = threadIdx.x * 4;
    int head = j >> 6;
    int nc = ((token % Sn) >> 9) + 1;   // tile>>2 + 1
    float a0 = 0.f, a1 = 0.f, a2 = 0.f, a3 = 0.f, l = 0.f;
    for (int cc = 0; cc < nc; ++cc) {
        ushort4 o4 = *(const ushort4*)(opart + ((size_t)cc * ROWS + token) * 1024 + j);
        a0 += b2f(o4.x); a1 += b2f(o4.y); a2 += b2f(o4.z); a3 += b2f(o4.w);
        l  += lpart[((size_t)cc * ROWS + token) * NHn + head];
    }
    float rin = 1.f / l;
    ushort4 out;
    out.x = f2bf(a0 * rin); out.y = f2bf(a1 * rin);
    out.z = f2bf(a2 * rin); out.w = f2bf(a3 * rin);
    *(ushort4*)(attb + (size_t)token * 1024 + j) = out;
}

// ---------------- LM head loss reductions (bf16 chunk) ----------------
__global__ void loss_init_kernel(float* __restrict__ m, float* __restrict__ s,
                                 float* __restrict__ tg) {
    int i = blockIdx.x * 256 + threadIdx.x;
    if (i < ROWS) { m[i] = -INFINITY; s[i] = 0.f; tg[i] = 0.f; }
}

__global__ __launch_bounds__(256)
void chunk_reduce_kernel(const ush* __restrict__ Cc, int Nc, int c0,
                         const int* __restrict__ y, float* __restrict__ m,
                         float* __restrict__ s, float* __restrict__ tg) {
    __shared__ float red[4];
    int r = blockIdx.x, tid = threadIdx.x;
    const ush* row = Cc + (size_t)r * VCHUNK;
    float v[16];
    float mx = -INFINITY;
#pragma unroll
    for (int t = 0; t < 16; ++t) {
        int j = tid + t * 256;
        v[t] = (j < Nc) ? b2f(row[j]) : -INFINITY;
        mx = fmaxf(mx, v[t]);
    }
    mx = block_max256(mx, red);
    float se = 0.f;
#pragma unroll
    for (int t = 0; t < 16; ++t)
        se += __expf(v[t] - mx);      // exp(-inf)=0 for padding
    se = block_sum256(se, red);
    if (tid == 0) {
        float mo = m[r];
        float mn = fmaxf(mo, mx);
        s[r] = s[r] * __expf(mo - mn) + se * __expf(mx - mn);
        m[r] = mn;
        int t = y[r] - c0;
        if (t >= 0 && t < Nc) tg[r] = b2f(row[t]);
    }
}

__global__ __launch_bounds__(256)
void loss_final_kernel(const float* __restrict__ m, const float* __restrict__ s,
                       const float* __restrict__ tg, float* __restrict__ out) {
    __shared__ float red[4];
    float part = 0.f;
    for (int r = threadIdx.x; r < ROWS; r += 256)
        part += m[r] + logf(s[r]) - tg[r];
    part = block_sum256(part, red);
    if (threadIdx.x == 0) out[0] = part * (1.f / ROWS);
}

// ---------------- host orchestration ----------------
extern "C" void kernel_launch(void* const* d_in, const int* in_sizes, int n_in,
                              void* d_out, int out_size, void* d_ws, size_t ws_size,
                              hipStream_t stream) {
    const int*   ids = (const int*)d_in[0];
    const int*   yv  = (const int*)d_in[1];
    const float* ue  = (const float*)d_in[2];
    const float* be  = (const float*)d_in[3];
    const float* Wq  = (const float*)d_in[4];
    const float* Wk  = (const float*)d_in[5];
    const float* Wv  = (const float*)d_in[6];
    const float* Wo  = (const float*)d_in[7];
    const float* qg  = (const float*)d_in[8];
    const float* asc = (const float*)d_in[9];
    const float* msc = (const float*)d_in[10];
    const float* rm  = (const float*)d_in[11];
    const float* Wf  = (const float*)d_in[12];
    const float* Wo2 = (const float*)d_in[13];
    const float* sw  = (const float*)d_in[14];
    (void)in_sizes; (void)n_in; (void)out_size; (void)ws_size;

    char* wsb = (char*)d_ws;
    size_t off = 0;
    auto alloc = [&](size_t bytes) {
        void* p = (void*)(wsb + off);
        off += ((bytes + 255) & ~size_t(255));
        return p;
    };
    // total ~297 MB (round-1's 312 MB layout fit; round-2's 443 MB crashed)
    float* h    = (float*)alloc((size_t)ROWS * Dm * 4);                // 16 MB
    float* h0   = (float*)alloc((size_t)ROWS * Dm * 4);                // 16 MB
    float* cosb = (float*)alloc((size_t)Sn * 32 * 4);
    float* sinb = (float*)alloc((size_t)Sn * 32 * 4);
    float* mrow = (float*)alloc(ROWS * 4);
    float* srow = (float*)alloc(ROWS * 4);
    float* tgv  = (float*)alloc(ROWS * 4);
    float* lpart= (float*)alloc((size_t)4 * ROWS * NHn * 4);           // 1 MB
    ush* skb  = (ush*)alloc((size_t)Ln * ROWS * Dm * 2);   // 48 MB bf16 skips
    ush* xnb  = (ush*)alloc((size_t)ROWS * Dm * 2);        // 8 MB
    // qkvb + hidb contiguous: their 36 MB region is aliased by opart (32 MB)
    ush* qkvb = (ush*)alloc((size_t)ROWS * 1536 * 2);      // 12 MB
    ush* hidb = (ush*)alloc((size_t)ROWS * 3 * Dm * 2);    // 24 MB
    ush* opart = qkvb;                                     // alias (dead by attn time)
    ush* qbf  = (ush*)alloc((size_t)ROWS * Dm * 2);        // 8 MB
    ush* kbf  = (ush*)alloc((size_t)ROWS * 256 * 2);       // 2 MB
    ush* vtb  = (ush*)alloc((size_t)256 * ROWS * 2);       // 2 MB
    ush* attb = (ush*)alloc((size_t)ROWS * Dm * 2);        // 8 MB
    ush* wall = (ush*)alloc((size_t)Ln * 8704 * 1024 * 2); // 102 MB (all layers)
    ush* ueb  = (ush*)alloc((size_t)VPAD * 512 * 2);       // 49.2 MB
    // bf16 LM-head chunk (32 MB) aliases skb (skips dead by then)
    ush* chunk = skb;

    auto cvt = [&](const float* s, ush* d, size_t n) {
        int n4 = (int)(n / 4);
        cvt_bf16_kernel<<<(n4 + 255) / 256, 256, 0, stream>>>(s, d, n4);
    };

    // one-time conversions: all layers' weights persist in bf16
    for (int l = 0; l < Ln; ++l) {
        ush* wl = wall + (size_t)l * 8704 * 1024;
        cvt(Wq + (size_t)l * Dm * Dm,      wl,              (size_t)Dm * Dm);
        cvt(Wk + (size_t)l * 256 * Dm,     wl + 1024 * Dm,  (size_t)256 * Dm);
        cvt(Wv + (size_t)l * 256 * Dm,     wl + 1280 * Dm,  (size_t)256 * Dm);
        cvt(Wo + (size_t)l * Dm * Dm,      wl + 1536 * Dm,  (size_t)Dm * Dm);
        cvt(Wf + (size_t)l * 3 * Dm * Dm,  wl + 2560 * Dm,  (size_t)3 * Dm * Dm);
        cvt(Wo2 + (size_t)l * 3 * Dm * Dm, wl + 5632 * Dm,  (size_t)3 * Dm * Dm);
    }
    cvt(ue, ueb, (size_t)VSn * 512);
    zpad_kernel<<<((VPAD - VSn) * 512 + 255) / 256, 256, 0, stream>>>(
        ueb + (size_t)VSn * 512, (VPAD - VSn) * 512);

    rope_kernel<<<(Sn * 32 + 255) / 256, 256, 0, stream>>>(cosb, sinb);
    embed_kernel<<<ROWS, 256, 0, stream>>>(ids, ue, be, h, h0);

    auto run_block = [&](int l, ush* dup, const ush* skip, const float* swv) {
        ush* wl    = wall + (size_t)l * 8704 * 1024;
        ush* wqkvb = wl;
        ush* wob   = wl + (size_t)1536 * 1024;
        ush* wfb   = wl + (size_t)2560 * 1024;
        ush* wo2b  = wl + (size_t)5632 * 1024;

        if (skip)
            resmix_kernel<true><<<ROWS, 256, 0, stream>>>(
                h, h0, rm + (size_t)l * 2 * Dm, xnb, skip, swv);
        else
            resmix_kernel<false><<<ROWS, 256, 0, stream>>>(
                h, h0, rm + (size_t)l * 2 * Dm, xnb, nullptr, nullptr);
        gemm_k<64, 0><<<dim3(ROWS / 64, 1536 / 128), 256, 0, stream>>>(
            xnb, wqkvb, qkvb, ROWS, 1536, Dm, Dm, Dm, 1536, nullptr, nullptr, nullptr);
        qknorm_rope_kernel<<<ROWS * (NHn + NKVn) / 4, 256, 0, stream>>>(
            qkvb, qbf, kbf, cosb, sinb, qg + (size_t)l * NHn);
        vtrans_kernel<<<dim3(ROWS / 32, 8), 256, 0, stream>>>(qkvb, vtb);
        attn_mfma_kernel<<<Bn * NHn * 40, 256, 0, stream>>>(
            qbf, kbf, vtb, opart, lpart, qg + (size_t)l * NHn);
        attn_combine_kernel<<<ROWS, 256, 0, stream>>>(opart, lpart, attb);
        gemm_k<64, 3><<<dim3(ROWS / 64, Dm / 128), 256, 0, stream>>>(
            attb, wob, nullptr, ROWS, Dm, Dm, Dm, Dm, Dm,
            h, asc + (size_t)l * Dm, nullptr);
        rmsn_kernel<<<ROWS, 256, 0, stream>>>(h, xnb);
        gemm_k<128, 1><<<dim3(ROWS / 128, 3 * Dm / 128), 256, 0, stream>>>(
            xnb, wfb, hidb, ROWS, 3 * Dm, Dm, Dm, Dm, 3 * Dm, nullptr, nullptr, nullptr);
        gemm_k<64, 3><<<dim3(ROWS / 64, Dm / 128), 256, 0, stream>>>(
            hidb, wo2b, nullptr, ROWS, Dm, 3 * Dm, 3 * Dm, 3 * Dm, Dm,
            h, msc + (size_t)l * Dm, dup);
    };

    for (int l = 0; l < Ln; ++l)
        run_block(l, skb + (size_t)l * ROWS * Dm, nullptr, nullptr);
    for (int i = 0; i < Ln; ++i) {
        int j = Ln - 1 - i;
        run_block(j, nullptr, skb + (size_t)j * ROWS * Dm, sw + (size_t)i * Dm);
    }

    // final norm + LM head (bf16 chunk aliases skb)
    rmsn_kernel<<<ROWS, 256, 0, stream>>>(h, xnb);
    loss_init_kernel<<<(ROWS + 255) / 256, 256, 0, stream>>>(mrow, srow, tgv);
    for (int c0 = 0; c0 < VSn; c0 += VCHUNK) {
        int Nc = (VSn - c0 < VCHUNK) ? (VSn - c0) : VCHUNK;
        int Ng = (VPAD - c0 < VCHUNK) ? (VPAD - c0) : VCHUNK;   // mult of 128
        gemm_k<128, 2><<<dim3(ROWS / 128, Ng / 128), 256, 0, stream>>>(
            xnb, ueb + (size_t)c0 * 512, chunk, ROWS, Ng, 512, Dm, 512, VCHUNK,
            nullptr, nullptr, nullptr);
        chunk_reduce_kernel<<<ROWS, 256, 0, stream>>>(chunk, Nc, c0, yv, mrow, srow, tgv);
    }
    loss_final_kernel<<<1, 256, 0, stream>>>(mrow, srow, tgv, (float*)d_out);
}